// Round 4
// baseline (30.414 us; speedup 1.0000x reference)
//
#include <hip/hip_runtime.h>
#include <hip/hip_bf16.h>

#define INF_SENT 1.0e6f
#define ALPHA 1.0f
#define INV_BETA 0.5f

#define B_ 16
#define H_ 256
#define W_ 256
#define SEG 8
#define NSEG 32           // H_/SEG
#define NBLK (B_ * NSEG)  // 512 fused blocks

// ---------------------------------------------------------------------------
// K1a: per-segment summaries for the vertical prefix/suffix min, and reset
// the completion counter used by the fused kernel's last-block reduction.
//   sumA[b,s,j] = min_{i in seg} (init[i] - i)   (init = mask?0:1e6)
//   sumB[b,s,j] = min_{i in seg} (init[i] + i)
// ---------------------------------------------------------------------------
__global__ void edt_seg_summary(const int* __restrict__ mask,
                                float* __restrict__ sumA,
                                float* __restrict__ sumB,
                                unsigned int* __restrict__ counter) {
    const int bs = blockIdx.x;
    if (bs == 0 && threadIdx.x == 0) counter[0] = 0u;
    const int b  = bs >> 5;
    const int s  = bs & (NSEG - 1);
    const int j  = threadIdx.x;
    const int i0 = s * SEG;
    const long base = ((long)b * H_ + i0) * W_ + j;

    float mA = 1e30f, mB = 1e30f;
    #pragma unroll
    for (int r = 0; r < SEG; ++r) {
        float init = mask[base + (long)r * W_] ? 0.0f : INF_SENT;
        float fi = (float)(i0 + r);
        mA = fminf(mA, init - fi);
        mB = fminf(mB, init + fi);
    }
    sumA[(long)bs * W_ + j] = mA;
    sumB[(long)bs * W_ + j] = mB;
}

// ---------------------------------------------------------------------------
// Fused kernel: carries -> in-register vertical scan (exact 1D EDT) -> LDS
// row tiles -> adaptive exact horizontal min -> CE + weight -> block partial
// -> deterministic last-block final reduction.
//
// Exactness of the outward-expansion early exit: every skipped term
// fl(g2[k]+r2) >= r2 >= best  (RN monotone, operands non-negative, r2
// representable), so the skipped terms cannot lower the min.
// ---------------------------------------------------------------------------
__global__ void fused_loss_kernel(const float* __restrict__ pred,
                                  const int* __restrict__ mask,
                                  const float* __restrict__ sumA,
                                  const float* __restrict__ sumB,
                                  float* __restrict__ partials,
                                  unsigned int* __restrict__ counter,
                                  float* __restrict__ out,
                                  float scale) {
    const int bs = blockIdx.x;
    const int b  = bs >> 5;
    const int s  = bs & (NSEG - 1);
    const int j  = threadIdx.x;
    const int i0 = s * SEG;
    const long base = ((long)b * H_ + i0) * W_ + j;

    __shared__ float s_g2[SEG][W_];
    __shared__ float s_part[4];
    __shared__ float s_part2[4];
    __shared__ int   s_flag;

    // carries from other segments of this (b, j) column
    float carryP = 1e30f;
    for (int sp = 0; sp < s; ++sp)
        carryP = fminf(carryP, sumA[((long)b * NSEG + sp) * W_ + j]);
    float carryS = 1e30f;
    for (int sp = s + 1; sp < NSEG; ++sp)
        carryS = fminf(carryS, sumB[((long)b * NSEG + sp) * W_ + j]);

    float init[SEG];
    #pragma unroll
    for (int r = 0; r < SEG; ++r)
        init[r] = mask[base + (long)r * W_] ? 0.0f : INF_SENT;

    // exact vertical distances (bitwise equal to reference fmin recurrences)
    float F[SEG];
    float P = carryP;
    #pragma unroll
    for (int r = 0; r < SEG; ++r) {
        float fi = (float)(i0 + r);
        P = fminf(P, init[r] - fi);
        F[r] = fi + P;
    }
    float S = carryS;
    #pragma unroll
    for (int r = SEG - 1; r >= 0; --r) {
        float fi = (float)(i0 + r);
        S = fminf(S, init[r] + fi);
        float g = fminf(F[r], S - fi);
        s_g2[r][j] = g * g;
    }
    __syncthreads();

    // per-row: adaptive exact horizontal min + CE + weight, accumulate
    float vsum = 0.0f;
    #pragma unroll
    for (int r = 0; r < SEG; ++r) {
        float best = s_g2[r][j];
        for (int d = 1; d < W_; ++d) {
            float d2 = (float)(d * d);
            if (d2 >= best) break;
            int kl = j - d, kr = j + d;
            if (kl >= 0)  best = fminf(best, s_g2[r][kl] + d2);
            if (kr < W_)  best = fminf(best, s_g2[r][kr] + d2);
        }
        float w = expf(-sqrtf(best) * INV_BETA);   // 0 when no bright points

        const int i = i0 + r;
        const long pbase = (((long)b * 2) * H_ + i) * W_ + j;
        float p0 = pred[pbase];
        float p1 = pred[pbase + (long)H_ * W_];
        float m  = fmaxf(p0, p1);
        float lse = m + logf(expf(p0 - m) + expf(p1 - m));
        float ce  = lse - ((init[r] == 0.0f) ? p1 : p0);

        vsum += ce * (1.0f + ALPHA * w);
    }

    // block reduction
    for (int off = 32; off > 0; off >>= 1)
        vsum += __shfl_down(vsum, off, 64);
    const int lane = j & 63;
    const int wid  = j >> 6;
    if (lane == 0) s_part[wid] = vsum;
    __syncthreads();
    if (j == 0) {
        partials[bs] = s_part[0] + s_part[1] + s_part[2] + s_part[3];
        __threadfence();
        unsigned int old = atomicAdd(counter, 1u);
        s_flag = (old == NBLK - 1) ? 1 : 0;
    }
    __syncthreads();

    // deterministic last-block final reduction (fixed-order tree)
    if (s_flag) {
        __threadfence();
        float v2 = partials[j] + partials[j + 256];
        for (int off = 32; off > 0; off >>= 1)
            v2 += __shfl_down(v2, off, 64);
        if (lane == 0) s_part2[wid] = v2;
        __syncthreads();
        if (j == 0)
            out[0] = (s_part2[0] + s_part2[1] + s_part2[2] + s_part2[3]) * scale;
    }
}

extern "C" void kernel_launch(void* const* d_in, const int* in_sizes, int n_in,
                              void* d_out, int out_size, void* d_ws, size_t ws_size,
                              hipStream_t stream) {
    const float* pred = (const float*)d_in[0];          // [B,2,H,W] f32
    const int*   mask = (const int*)d_in[1];            // [B,H,W] i32
    float* out = (float*)d_out;

    const size_t n_sum = (size_t)B_ * NSEG * W_;        // 128K floats each

    float* sumA             = (float*)d_ws;
    float* sumB             = sumA + n_sum;
    float* partials         = sumB + n_sum;             // NBLK floats
    unsigned int* counter   = (unsigned int*)(partials + NBLK);

    edt_seg_summary<<<NBLK, W_, 0, stream>>>(mask, sumA, sumB, counter);
    fused_loss_kernel<<<NBLK, W_, 0, stream>>>(pred, mask, sumA, sumB,
                                               partials, counter, out,
                                               1.0f / (float)(B_ * H_ * W_));
}

// Round 5
// 18.856 us; speedup vs baseline: 1.6130x; 1.6130x over previous
//
#include <hip/hip_runtime.h>
#include <hip/hip_bf16.h>

#define INF_SENT 1.0e6f
#define ALPHA 1.0f
#define INV_BETA 0.5f

#define B_ 16
#define H_ 256
#define W_ 256
#define SEG 8
#define NSEG 32           // H_/SEG
#define NBLK (B_ * NSEG)  // 512 blocks

// ---------------------------------------------------------------------------
// K1: per-segment summaries for the vertical prefix/suffix min.
//   sumA[b,s,j] = min_{i in seg} (init[i] - i)   (init = mask?0:1e6)
//   sumB[b,s,j] = min_{i in seg} (init[i] + i)
// ---------------------------------------------------------------------------
__global__ void edt_seg_summary(const int* __restrict__ mask,
                                float* __restrict__ sumA,
                                float* __restrict__ sumB) {
    const int bs = blockIdx.x;
    const int b  = bs >> 5;
    const int s  = bs & (NSEG - 1);
    const int j  = threadIdx.x;
    const int i0 = s * SEG;
    const long base = ((long)b * H_ + i0) * W_ + j;

    float mA = 1e30f, mB = 1e30f;
    #pragma unroll
    for (int r = 0; r < SEG; ++r) {
        float init = mask[base + (long)r * W_] ? 0.0f : INF_SENT;
        float fi = (float)(i0 + r);
        mA = fminf(mA, init - fi);
        mB = fminf(mB, init + fi);
    }
    sumA[(long)bs * W_ + j] = mA;
    sumB[(long)bs * W_ + j] = mB;
}

// ---------------------------------------------------------------------------
// K2: fused per-segment loss. Carries (constant-trip predicated min over all
// 32 segment summaries -> 64 independent, pipelined loads) -> in-register
// vertical scan (exact 1D EDT) -> LDS row tiles -> adaptive exact horizontal
// min -> CE + weight -> one partial per block. No atomics, no fences.
//
// Early-exit exactness: every skipped term fl(g2[k]+d2) >= d2 >= best
// (round-to-nearest is monotone, operands non-negative, d2 representable),
// so skipped terms cannot lower the min.
// ---------------------------------------------------------------------------
__global__ void fused_loss_kernel(const float* __restrict__ pred,
                                  const int* __restrict__ mask,
                                  const float* __restrict__ sumA,
                                  const float* __restrict__ sumB,
                                  float* __restrict__ partials) {
    const int bs = blockIdx.x;
    const int b  = bs >> 5;
    const int s  = bs & (NSEG - 1);
    const int j  = threadIdx.x;
    const int i0 = s * SEG;
    const long base = ((long)b * H_ + i0) * W_ + j;

    __shared__ float s_g2[SEG][W_];
    __shared__ float s_part[4];

    // carries from the other segments of this (b, j) column
    const float* sA = sumA + (long)b * NSEG * W_ + j;
    const float* sB = sumB + (long)b * NSEG * W_ + j;
    float carryP = 1e30f, carryS = 1e30f;
    #pragma unroll
    for (int sp = 0; sp < NSEG; ++sp) {
        float a  = sA[(long)sp * W_];
        float bb = sB[(long)sp * W_];
        carryP = fminf(carryP, (sp < s) ? a  : 1e30f);
        carryS = fminf(carryS, (sp > s) ? bb : 1e30f);
    }

    float init[SEG];
    #pragma unroll
    for (int r = 0; r < SEG; ++r)
        init[r] = mask[base + (long)r * W_] ? 0.0f : INF_SENT;

    // exact vertical distances
    float F[SEG];
    float P = carryP;
    #pragma unroll
    for (int r = 0; r < SEG; ++r) {
        float fi = (float)(i0 + r);
        P = fminf(P, init[r] - fi);
        F[r] = fi + P;
    }
    float S = carryS;
    #pragma unroll
    for (int r = SEG - 1; r >= 0; --r) {
        float fi = (float)(i0 + r);
        S = fminf(S, init[r] + fi);
        float g = fminf(F[r], S - fi);
        s_g2[r][j] = g * g;
    }
    __syncthreads();

    // per-row adaptive exact horizontal min + CE + weight
    float vsum = 0.0f;
    #pragma unroll
    for (int r = 0; r < SEG; ++r) {
        float best = s_g2[r][j];
        for (int d = 1; d < W_; ++d) {
            float d2 = (float)(d * d);
            if (d2 >= best) break;
            int kl = j - d, kr = j + d;
            if (kl >= 0)  best = fminf(best, s_g2[r][kl] + d2);
            if (kr < W_)  best = fminf(best, s_g2[r][kr] + d2);
        }
        float w = __expf(-sqrtf(best) * INV_BETA);   // 0 when no bright points

        const int i = i0 + r;
        const long pbase = (((long)b * 2) * H_ + i) * W_ + j;
        float p0 = pred[pbase];
        float p1 = pred[pbase + (long)H_ * W_];
        // 2-class CE = softplus(-(p_t - p_other))
        float z  = (init[r] == 0.0f) ? (p1 - p0) : (p0 - p1);
        float ce = __logf(1.0f + __expf(-z));

        vsum += ce * (1.0f + ALPHA * w);
    }

    // block reduction -> one partial
    for (int off = 32; off > 0; off >>= 1)
        vsum += __shfl_down(vsum, off, 64);
    const int lane = j & 63;
    const int wid  = j >> 6;
    if (lane == 0) s_part[wid] = vsum;
    __syncthreads();
    if (j == 0)
        partials[bs] = s_part[0] + s_part[1] + s_part[2] + s_part[3];
}

// ---------------------------------------------------------------------------
// K3: deterministic final reduction of NBLK partials -> mean.
// ---------------------------------------------------------------------------
__global__ void final_reduce_kernel(const float* __restrict__ partials,
                                    float* __restrict__ out,
                                    float scale) {
    __shared__ float s_part[8];
    const int t = threadIdx.x;           // 512 threads
    float v = partials[t];
    for (int off = 32; off > 0; off >>= 1)
        v += __shfl_down(v, off, 64);
    const int lane = t & 63;
    const int wid  = t >> 6;
    if (lane == 0) s_part[wid] = v;
    __syncthreads();
    if (t == 0) {
        float ssum = 0.0f;
        #pragma unroll
        for (int k = 0; k < 8; ++k) ssum += s_part[k];
        out[0] = ssum * scale;
    }
}

extern "C" void kernel_launch(void* const* d_in, const int* in_sizes, int n_in,
                              void* d_out, int out_size, void* d_ws, size_t ws_size,
                              hipStream_t stream) {
    const float* pred = (const float*)d_in[0];          // [B,2,H,W] f32
    const int*   mask = (const int*)d_in[1];            // [B,H,W] i32
    float* out = (float*)d_out;

    const size_t n_sum = (size_t)B_ * NSEG * W_;        // 128K floats each

    float* sumA     = (float*)d_ws;
    float* sumB     = sumA + n_sum;
    float* partials = sumB + n_sum;                     // NBLK floats

    edt_seg_summary<<<NBLK, W_, 0, stream>>>(mask, sumA, sumB);
    fused_loss_kernel<<<NBLK, W_, 0, stream>>>(pred, mask, sumA, sumB, partials);
    final_reduce_kernel<<<1, 512, 0, stream>>>(partials, out,
                                               1.0f / (float)(B_ * H_ * W_));
}